// Round 4
// baseline (749.039 us; speedup 1.0000x reference)
//
#include <hip/hip_runtime.h>

typedef __attribute__((ext_vector_type(8))) short short8;
typedef __attribute__((ext_vector_type(4))) float f32x4;
typedef __attribute__((ext_vector_type(4))) int i32x4;

#define NPIX 65536
#define KP 136
#define RED_KSUM 0
#define RED_VSUM 512
#define RED_AGG 1024

__device__ __forceinline__ float b2f(unsigned short u) {
  union { unsigned int i; float f; } z; z.i = ((unsigned int)u) << 16; return z.f;
}
__device__ __forceinline__ unsigned short f2b(float f) {
  union { float f; unsigned int i; } z; z.f = f;
  unsigned int r = z.i + 0x7fffu + ((z.i >> 16) & 1u);
  return (unsigned short)(r >> 16);
}
__device__ __forceinline__ unsigned int packbf(float a, float b) {
  return (unsigned int)f2b(a) | ((unsigned int)f2b(b) << 16);
}
// packed f32->bf16 (RNE), 1 instr per 2 values
__device__ __forceinline__ int cvtpk(float a, float b) {
  int r;
  asm("v_cvt_pk_bf16_f32 %0, %1, %2" : "=v"(r) : "v"(a), "v"(b));
  return r;
}

// Build MFMA A-fragment weights (bf16) for both convs:
// wA[conv][tap][kb][mt][lane][j] = W[o=mt*16+(lane&15)][c=kb*32+(lane>>4)*8+j][tap]
// Also zero the reduction region (ws is 0xAA-poisoned before every call).
__global__ __launch_bounds__(256) void prep_kernel(
    const float* __restrict__ W1, const float* __restrict__ W2,
    unsigned short* __restrict__ wA, float* __restrict__ red)
{
  const int i = blockIdx.x * 256 + threadIdx.x;
  if (i < 73728) {
    const float* W = (i < 36864) ? W1 : W2;
    const int e = (i < 36864) ? i : (i - 36864);
    const int j    = e & 7;
    const int lane = (e >> 3) & 63;
    const int mt   = (e >> 9) & 3;
    const int kb   = (e >> 11) & 1;
    const int tap  = e >> 12;                 // 0..8 = dy*3+dx
    const int o = mt * 16 + (lane & 15);
    const int c = kb * 32 + ((lane >> 4) << 3) + j;
    wA[i] = f2b(W[o * 576 + c * 9 + tap]);
  } else if (i < 73728 + 33792) {
    red[i - 73728] = 0.0f;
  }
}

// Pass 1: Q/K/V via 16x16x32 bf16 MFMA, 128-px staging rounds.
// Wave = 32 px (acc[4][2]). Q: L2-normalized, wave-private LDS transpose,
// dense NHWC bf16 store. K: normalized, staged bf16 [64ch][KP px] LDS.
// V: staged likewise. agg_kv = Kn.V^T via MFMA over k=px (4 k-steps/round).
// 34.8KB LDS -> 4 blocks/CU; next-round x fragments prefetched into bf
// right after staging (overlaps agg MFMA + barrier with HBM latency).
#define LOADBF(PX)                                                             \
    {                                                                          \
      _Pragma("unroll")                                                        \
      for (int nt = 0; nt < 2; ++nt) {                                         \
        const float* xp = x + xb + (size_t)(g * 8) * NPIX + (PX) + nt * 16 + l15; \
        _Pragma("unroll")                                                      \
        for (int kb = 0; kb < 2; ++kb) {                                       \
          float f[8];                                                          \
          _Pragma("unroll")                                                    \
          for (int j = 0; j < 8; ++j)                                          \
            f[j] = xp[(size_t)(kb * 32 + j) * NPIX];                           \
          union { i32x4 i; short8 s; } u2;                                     \
          u2.i.x = cvtpk(f[0], f[1]); u2.i.y = cvtpk(f[2], f[3]);              \
          u2.i.z = cvtpk(f[4], f[5]); u2.i.w = cvtpk(f[6], f[7]);              \
          bf[nt][kb] = u2.s;                                                   \
        }                                                                      \
      }                                                                        \
    }

#define PROJ2(WM, BM)                                                          \
    {                                                                          \
      _Pragma("unroll")                                                        \
      for (int mt = 0; mt < 4; ++mt) {                                         \
        const f32x4 bb = *(const f32x4*)((BM) + mt * 16 + g * 4);              \
        acc[mt][0] = bb; acc[mt][1] = bb;                                      \
      }                                                                        \
      _Pragma("unroll")                                                        \
      for (int kb = 0; kb < 2; ++kb) {                                         \
        short8 af[4];                                                          \
        _Pragma("unroll")                                                      \
        for (int mt = 0; mt < 4; ++mt) {                                       \
          const float* wp = (WM) + mt * 1024 + wrow + kb * 32;                 \
          const f32x4 w0 = *(const f32x4*)wp;                                  \
          const f32x4 w1 = *(const f32x4*)(wp + 4);                            \
          union { i32x4 i; short8 s; } uw;                                     \
          uw.i.x = cvtpk(w0.x, w0.y); uw.i.y = cvtpk(w0.z, w0.w);              \
          uw.i.z = cvtpk(w1.x, w1.y); uw.i.w = cvtpk(w1.z, w1.w);              \
          af[mt] = uw.s;                                                       \
        }                                                                      \
        _Pragma("unroll")                                                      \
        for (int mt = 0; mt < 4; ++mt)                                         \
          _Pragma("unroll")                                                    \
          for (int nt = 0; nt < 2; ++nt)                                       \
            acc[mt][nt] = __builtin_amdgcn_mfma_f32_16x16x32_bf16(             \
                af[mt], bf[nt][kb], acc[mt][nt], 0, 0, 0);                     \
      }                                                                        \
    }

__global__ __launch_bounds__(256, 4) void qkv_kernel(
    const float* __restrict__ x,
    const float* __restrict__ Wq, const float* __restrict__ bq,
    const float* __restrict__ Wk, const float* __restrict__ bk,
    const float* __restrict__ Wv, const float* __restrict__ bv,
    unsigned short* __restrict__ Qn, float* __restrict__ red)
{
  __shared__ __align__(16) unsigned short sh[2 * 64 * KP];   // 34816 B
  unsigned short* ks = sh;
  unsigned short* vs = sh + 64 * KP;
  const int b = blockIdx.y;
  const int t = threadIdx.x;
  const int w = t >> 6, l = t & 63, g = l >> 4, l15 = l & 15;
  const int wrow = l15 * 64 + g * 8;     // per-lane W row-slice base (floats)
  const size_t xb = (size_t)b * 64 * NPIX;

  const f32x4 zero = {0.f, 0.f, 0.f, 0.f};
  f32x4 agg[4]  = {zero, zero, zero, zero};
  f32x4 kacc[4] = {zero, zero, zero, zero};
  f32x4 vacc[4] = {zero, zero, zero, zero};

  short8 bf[2][2];
  LOADBF((blockIdx.x << 9) + (w << 5));          // prologue: rd=0 fragments

  for (int rd = 0; rd < 4; ++rd) {
    const int pxblk = (blockIdx.x << 9) + (rd << 7);
    const int pxw = pxblk + (w << 5);            // wave px base (32 px)

    f32x4 acc[4][2];

    // ---- Q: project, normalize, wave-private LDS transpose, NHWC store ----
    PROJ2(Wq, bq);
    {
      float rq[2];
#pragma unroll
      for (int nt = 0; nt < 2; ++nt) {
        float ss = 0.f;
#pragma unroll
        for (int mt = 0; mt < 4; ++mt)
#pragma unroll
          for (int r = 0; r < 4; ++r)
            ss = fmaf(acc[mt][nt][r], acc[mt][nt][r], ss);
        ss += __shfl_xor(ss, 16);
        ss += __shfl_xor(ss, 32);
        rq[nt] = rsqrtf(ss);
      }
      unsigned int* sw = (unsigned int*)sh + w * 1152;   // 32px * 36 uints
#pragma unroll
      for (int mt = 0; mt < 4; ++mt)
#pragma unroll
        for (int nt = 0; nt < 2; ++nt) {
          unsigned int* dst = sw + (nt * 16 + l15) * 36 + mt * 8 + g * 2;
          dst[0] = (unsigned)cvtpk(acc[mt][nt][0] * rq[nt],
                                   acc[mt][nt][1] * rq[nt]);
          dst[1] = (unsigned)cvtpk(acc[mt][nt][2] * rq[nt],
                                   acc[mt][nt][3] * rq[nt]);
        }
      const uint4* rr4 = (const uint4*)sh + w * 288;     // 32px * 9 uint4
#pragma unroll
      for (int k4 = 0; k4 < 4; ++k4) {
        const int p = (k4 << 3) + (l >> 3);
        const int ch8 = l & 7;
        *(uint4*)(Qn + ((size_t)b * NPIX + pxw + p) * 64 + ch8 * 8) =
            rr4[p * 9 + ch8];
      }
    }
    __syncthreads();   // all Q-scratch reads done before K/V staging writes

    // ---- K: project, normalize, ksum partials, stage to LDS ----
    PROJ2(Wk, bk);
    {
      float rk[2];
#pragma unroll
      for (int nt = 0; nt < 2; ++nt) {
        float ss = 0.f;
#pragma unroll
        for (int mt = 0; mt < 4; ++mt)
#pragma unroll
          for (int r = 0; r < 4; ++r)
            ss = fmaf(acc[mt][nt][r], acc[mt][nt][r], ss);
        ss += __shfl_xor(ss, 16);
        ss += __shfl_xor(ss, 32);
        rk[nt] = rsqrtf(ss);
      }
#pragma unroll
      for (int mt = 0; mt < 4; ++mt)
#pragma unroll
        for (int nt = 0; nt < 2; ++nt)
#pragma unroll
          for (int r = 0; r < 4; ++r) {
            const float kn = acc[mt][nt][r] * rk[nt];
            kacc[mt][r] += kn;
            ks[(mt * 16 + g * 4 + r) * KP + (w << 5) + nt * 16 + l15] =
                (unsigned short)cvtpk(kn, 0.f);
          }
    }

    // ---- V: project, vsum partials, stage to LDS ----
    PROJ2(Wv, bv);
    {
#pragma unroll
      for (int mt = 0; mt < 4; ++mt)
#pragma unroll
        for (int nt = 0; nt < 2; ++nt)
#pragma unroll
          for (int r = 0; r < 4; ++r) {
            const float vv = acc[mt][nt][r];
            vacc[mt][r] += vv;
            vs[(mt * 16 + g * 4 + r) * KP + (w << 5) + nt * 16 + l15] =
                (unsigned short)cvtpk(vv, 0.f);
          }
    }
    __syncthreads();

    // ---- prefetch next round's x fragments (bf free; overlaps agg) ----
    if (rd < 3) LOADBF(pxblk + 128 + (w << 5));

    // ---- agg_kv: MFMA over k = pixels (128 px this round, 4 k-steps) ----
#pragma unroll
    for (int s = 0; s < 4; ++s) {
      const short8 ak =
          *(const short8*)(ks + (w * 16 + l15) * KP + s * 32 + g * 8);
#pragma unroll
      for (int nt2 = 0; nt2 < 4; ++nt2) {
        const short8 bv8 =
            *(const short8*)(vs + (nt2 * 16 + l15) * KP + s * 32 + g * 8);
        agg[nt2] = __builtin_amdgcn_mfma_f32_16x16x32_bf16(
            ak, bv8, agg[nt2], 0, 0, 0);
      }
    }
    __syncthreads();   // agg reads done before next round's Q-scratch writes
  }

  // ---- reductions: ksum/vsum butterfly over l15, then global atomics ----
#pragma unroll
  for (int mt = 0; mt < 4; ++mt)
#pragma unroll
    for (int r = 0; r < 4; ++r) {
      float kv = kacc[mt][r], vv = vacc[mt][r];
#pragma unroll
      for (int d = 1; d < 16; d <<= 1) {
        kv += __shfl_xor(kv, d);
        vv += __shfl_xor(vv, d);
      }
      if (l15 == 0) {
        atomicAdd(red + RED_KSUM + b * 64 + mt * 16 + g * 4 + r, kv);
        atomicAdd(red + RED_VSUM + b * 64 + mt * 16 + g * 4 + r, vv);
      }
    }
  float* ab = red + RED_AGG + b * 4096;
#pragma unroll
  for (int nt = 0; nt < 4; ++nt)
#pragma unroll
    for (int r = 0; r < 4; ++r)
      atomicAdd(ab + (w * 16 + g * 4 + r) * 64 + nt * 16 + l15, agg[nt][r]);
}

// Prep2: per batch, C = Wr.agg^T (64x64) split into bf16 hi+residual in
// MFMA A-frag layout; u = Wr.vsum; ks2 = ksum + eps.
__global__ __launch_bounds__(256) void prep2_kernel(
    const float* __restrict__ Wr, const float* __restrict__ red,
    unsigned short* __restrict__ Cb, float* __restrict__ u,
    float* __restrict__ ks2)
{
  const int b = blockIdx.y;
  const int t = threadIdx.x;
  const int o = t & 63;
  const int kq = t >> 6;                 // 0..3
  const float* wr = Wr + o * 64;
  const float* agg = red + RED_AGG + b * 4096;
#pragma unroll
  for (int i = 0; i < 4; ++i) {
    const int k = blockIdx.x * 16 + kq * 4 + i;
    const float* ar = agg + k * 64;
    float s = 0.f;
#pragma unroll
    for (int v = 0; v < 64; ++v) s = fmaf(wr[v], ar[v], s);
    const int mt = o >> 4, kb = k >> 5;
    const int lane = (o & 15) | (((k >> 3) & 3) << 4);
    const int j = k & 7;
    const unsigned short c1 = f2b(s);
    const float r1 = s - b2f(c1);
    Cb[b * 4096 + ((kb * 4 + mt) * 64 + lane) * 8 + j] = c1;
    Cb[32768 + b * 4096 + ((kb * 4 + mt) * 64 + lane) * 8 + j] = f2b(r1);
  }
  if (blockIdx.x == 0 && t < 64) {
    const float* vsr = red + RED_VSUM + b * 64;
    float s = 0.f;
#pragma unroll
    for (int v = 0; v < 64; ++v) s = fmaf(Wr[t * 64 + v], vsr[v], s);
    u[b * 64 + t] = s;
    ks2[b * 64 + t] = red[RED_KSUM + b * 64 + t] + 1e-6f;
  }
}

// Pass 2 (MFMA): attn[o,n] = denom[n]*(u[o] + C[o,:].qn[:,n]) + br[o].
// C = C1 + C2 (bf16 split) -> fp32-accurate. denom from per-lane partial
// dot with ks2 + shfl_xor reduce. Output NHWC bf16 via wave-private LDS
// transpose (no barriers needed).
__global__ __launch_bounds__(256, 2) void attn_kernel(
    const unsigned short* __restrict__ Qn,   // NHWC bf16
    const unsigned short* __restrict__ Cb,   // C1||C2 A-frags
    const float* __restrict__ u,
    const float* __restrict__ ks2,
    const float* __restrict__ br,
    unsigned short* __restrict__ attn)       // NHWC bf16
{
  __shared__ __align__(16) unsigned short att[256 * 72];
  const int b = blockIdx.y;
  const int t = threadIdx.x;
  const int w = t >> 6, l = t & 63, g = l >> 4, l15 = l & 15;

  short8 af[2][2][4];  // [lvl][kb][mt]
#pragma unroll
  for (int lvl = 0; lvl < 2; ++lvl)
#pragma unroll
    for (int kb = 0; kb < 2; ++kb)
#pragma unroll
      for (int mt = 0; mt < 4; ++mt)
        af[lvl][kb][mt] = *(const short8*)(
            Cb + lvl * 32768 + b * 4096 + ((kb * 4 + mt) * 64 + l) * 8);
  f32x4 uu[4], brf[4];
#pragma unroll
  for (int mt = 0; mt < 4; ++mt) {
    uu[mt]  = *(const f32x4*)(u + b * 64 + mt * 16 + g * 4);
    brf[mt] = *(const f32x4*)(br + mt * 16 + g * 4);
  }
  float ksl[16];
#pragma unroll
  for (int kb = 0; kb < 2; ++kb)
#pragma unroll
    for (int j = 0; j < 8; ++j)
      ksl[kb * 8 + j] = ks2[b * 64 + kb * 32 + g * 8 + j];

  for (int it = 0; it < 4; ++it) {
    const int pxw = (blockIdx.x << 10) + (it << 8) + (w << 6);
    short8 qf[4][2];
    float denom[4];
#pragma unroll
    for (int nt = 0; nt < 4; ++nt) {
      const unsigned short* qp =
          Qn + ((size_t)b * NPIX + pxw + nt * 16 + l15) * 64 + g * 8;
      qf[nt][0] = *(const short8*)qp;
      qf[nt][1] = *(const short8*)(qp + 32);
      float ss = 0.f;
#pragma unroll
      for (int kb = 0; kb < 2; ++kb)
#pragma unroll
        for (int j = 0; j < 8; ++j)
          ss = fmaf(b2f((unsigned short)qf[nt][kb][j]), ksl[kb * 8 + j], ss);
      ss += __shfl_xor(ss, 16);
      ss += __shfl_xor(ss, 32);
      denom[nt] = 1.0f / (65536.0f + ss);
    }
    f32x4 acc[4][4];
#pragma unroll
    for (int mt = 0; mt < 4; ++mt)
#pragma unroll
      for (int nt = 0; nt < 4; ++nt) acc[mt][nt] = uu[mt];
#pragma unroll
    for (int kb = 0; kb < 2; ++kb)
#pragma unroll
      for (int mt = 0; mt < 4; ++mt)
#pragma unroll
        for (int nt = 0; nt < 4; ++nt) {
          acc[mt][nt] = __builtin_amdgcn_mfma_f32_16x16x32_bf16(
              af[0][kb][mt], qf[nt][kb], acc[mt][nt], 0, 0, 0);
          acc[mt][nt] = __builtin_amdgcn_mfma_f32_16x16x32_bf16(
              af[1][kb][mt], qf[nt][kb], acc[mt][nt], 0, 0, 0);
        }
    // epilogue: val = acc*denom + br; wave-private LDS transpose, dense store
    unsigned int* sw = (unsigned int*)att + w * 2304;
#pragma unroll
    for (int mt = 0; mt < 4; ++mt)
#pragma unroll
      for (int nt = 0; nt < 4; ++nt) {
        const int px = nt * 16 + l15;
        unsigned int* dst = sw + px * 36 + mt * 8 + g * 2;
        dst[0] = (unsigned)cvtpk(fmaf(acc[mt][nt][0], denom[nt], brf[mt][0]),
                                 fmaf(acc[mt][nt][1], denom[nt], brf[mt][1]));
        dst[1] = (unsigned)cvtpk(fmaf(acc[mt][nt][2], denom[nt], brf[mt][2]),
                                 fmaf(acc[mt][nt][3], denom[nt], brf[mt][3]));
      }
    const uint4* rr4 = (const uint4*)att + w * 576;
#pragma unroll
    for (int k8 = 0; k8 < 8; ++k8) {
      const int p = (k8 << 3) + (l >> 3);
      const int ch8 = l & 7;
      *(uint4*)(attn + ((size_t)b * NPIX + pxw + p) * 64 + ch8 * 8) =
          rr4[p * 9 + ch8];
    }
  }
}

// 3x3 SAME conv, 64->64 ch, bf16 MFMA implicit GEMM.
template <int EPI>
__global__ __launch_bounds__(256, 3) void conv3_kernel(
    const unsigned short* __restrict__ in,   // NHWC bf16
    const unsigned short* __restrict__ wA,   // A-frag weights bf16
    const float* __restrict__ bias,
    const float* __restrict__ xin,           // NCHW fp32 (EPI=1)
    unsigned short* __restrict__ outh,       // NHWC bf16 (EPI=0)
    float* __restrict__ outf)                // NCHW fp32 (EPI=1)
{
  __shared__ __align__(16) unsigned short tile[10 * 34 * 72];
  const int bz = blockIdx.z;
  const int ty0 = blockIdx.y << 3;
  const int tx0 = blockIdx.x << 5;
  const int tid = threadIdx.x;
  const size_t nb = (size_t)bz * NPIX;

  // ---- stage NHWC tile (halo=1, zero-pad SAME) ----
  for (int s = tid; s < 2720; s += 256) {
    const int g = s & 7;
    const int pix = s >> 3;          // 0..339
    const int xx = pix % 34;
    const int row = pix / 34;
    const int gx = tx0 + xx - 1;
    const int gy = ty0 + row - 1;
    uint4 v = {0u, 0u, 0u, 0u};
    if ((unsigned)gx < 256u && (unsigned)gy < 256u)
      v = *(const uint4*)(in + ((nb + (gy << 8) + gx) << 6) + (g << 3));
    *(uint4*)(tile + pix * 72 + (g << 3)) = v;
  }
  __syncthreads();

  const int w = tid >> 6, lane = tid & 63, q = lane >> 4, l = lane & 15;
  f32x4 acc[4][4];
  {
#pragma unroll
    for (int mt = 0; mt < 4; ++mt) {
      const f32x4 bb = *(const f32x4*)(bias + mt * 16 + q * 4);
#pragma unroll
      for (int nt = 0; nt < 4; ++nt) acc[mt][nt] = bb;
    }
  }
  const short8* tp = (const short8*)tile;   // 72 shorts = 9 short8 per pixel
  for (int tap = 0; tap < 9; ++tap) {
    const int dy = tap / 3, dx = tap - dy * 3;
#pragma unroll
    for (int kb = 0; kb < 2; ++kb) {
      const unsigned short* wp = wA + (tap * 2 + kb) * 2048 + lane * 8;
      short8 af[4];
#pragma unroll
      for (int mt = 0; mt < 4; ++mt) af[mt] = *(const short8*)(wp + mt * 512);
      short8 bf[4];
#pragma unroll
      for (int nt = 0; nt < 4; ++nt) {
        const int yl = (w << 1) + (nt >> 1) + dy;           // 0..9
        const int xl = ((nt & 1) << 4) + l + dx;            // 0..33
        bf[nt] = tp[(yl * 34 + xl) * 9 + (kb << 2) + q];
      }
#pragma unroll
      for (int mt = 0; mt < 4; ++mt)
#pragma unroll
        for (int nt = 0; nt < 4; ++nt)
          acc[mt][nt] = __builtin_amdgcn_mfma_f32_16x16x32_bf16(
              af[mt], bf[nt], acc[mt][nt], 0, 0, 0);
    }
  }

  if (EPI == 0) {
    // NHWC bf16 epilogue: transpose C-frag -> [pixel][o] in LDS, dense store
    __syncthreads();                          // all waves done reading tile
    unsigned int* wreg = (unsigned int*)tile + w * 2304;   // 64 px * 36 uints
#pragma unroll
    for (int mt = 0; mt < 4; ++mt)
#pragma unroll
      for (int nt = 0; nt < 4; ++nt) {
        const int p = ((nt >> 1) << 5) + ((nt & 1) << 4) + l;
        unsigned int* dst = wreg + p * 36 + (mt << 3) + (q << 1);
        dst[0] = packbf(acc[mt][nt][0], acc[mt][nt][1]);
        dst[1] = packbf(acc[mt][nt][2], acc[mt][nt][3]);
      }
    __syncthreads();
    const uint4* rreg = (const uint4*)tile + w * 576;      // 64 px * 9 uint4
#pragma unroll
    for (int k = 0; k < 8; ++k) {
      const int p = (k << 3) + (lane >> 3);
      const int ch = lane & 7;
      const int gx = tx0 + (p & 31);
      const int gy = ty0 + (w << 1) + (p >> 5);
      *(uint4*)(outh + ((nb + (gy << 8) + gx) << 6) + (ch << 3)) =
          rreg[p * 9 + ch];
    }
  } else {
    // fused epilogue: out = conv*x + x, NCHW fp32
#pragma unroll
    for (int mt = 0; mt < 4; ++mt)
#pragma unroll
      for (int nt = 0; nt < 4; ++nt) {
        const int gx = tx0 + ((nt & 1) << 4) + l;
        const int gy = ty0 + (w << 1) + (nt >> 1);
#pragma unroll
        for (int r = 0; r < 4; ++r) {
          const int o = (mt << 4) + (q << 2) + r;
          const size_t idx = (((size_t)bz * 64 + o) << 16) + (gy << 8) + gx;
          const float xo = xin[idx];
          outf[idx] = fmaf(acc[mt][nt][r], xo, xo);
        }
      }
  }
}

extern "C" void kernel_launch(void* const* d_in, const int* in_sizes, int n_in,
                              void* d_out, int out_size, void* d_ws, size_t ws_size,
                              hipStream_t stream) {
  (void)in_sizes; (void)n_in; (void)out_size; (void)ws_size;
  const float* x  = (const float*)d_in[0];
  const float* Wq = (const float*)d_in[1];
  const float* bq = (const float*)d_in[2];
  const float* Wk = (const float*)d_in[3];
  const float* bk = (const float*)d_in[4];
  const float* Wv = (const float*)d_in[5];
  const float* bv = (const float*)d_in[6];
  const float* Wr = (const float*)d_in[7];
  const float* br = (const float*)d_in[8];
  const float* W1 = (const float*)d_in[9];
  const float* b1 = (const float*)d_in[10];
  const float* W2 = (const float*)d_in[11];
  const float* b2 = (const float*)d_in[12];

  // ws layout: wA1 [0,73728B) | wA2 [73728,147456B) | red 33792 fp32 | bufA.
  // Cb/u/ks2 alias bufA's first 136KB: written by prep2, read by attn,
  // overwritten only later by conv3<0> (stream-serialized).
  unsigned short* wA1 = (unsigned short*)d_ws;
  unsigned short* wA2 = wA1 + 36864;
  float* red = (float*)((char*)d_ws + 147456);
  unsigned short* bufA = (unsigned short*)((char*)d_ws + 294912); // conv1 out NHWC bf16
  unsigned short* Cb = (unsigned short*)((char*)d_ws + 294912);
  float* u_  = (float*)((char*)d_ws + 294912 + 131072);
  float* ks2 = (float*)((char*)d_ws + 294912 + 133120);
  // d_out scratch: first half = attn NHWC bf16, second half = Qn NHWC bf16.
  unsigned short* bufB = (unsigned short*)d_out;
  unsigned short* bufQ = (unsigned short*)((char*)d_out + 67108864);

  prep_kernel<<<420, 256, 0, stream>>>(W1, W2, wA1, red);
  qkv_kernel<<<dim3(128, 8), 256, 0, stream>>>(x, Wq, bq, Wk, bk, Wv, bv, bufQ, red);
  prep2_kernel<<<dim3(4, 8), 256, 0, stream>>>(Wr, red, Cb, u_, ks2);
  attn_kernel<<<dim3(64, 8), 256, 0, stream>>>(bufQ, Cb, u_, ks2, br, bufB);
  conv3_kernel<0><<<dim3(8, 32, 8), 256, 0, stream>>>(
      bufB, wA1, b1, nullptr, bufA, nullptr);
  conv3_kernel<1><<<dim3(8, 32, 8), 256, 0, stream>>>(
      bufA, wA2, b2, x, nullptr, (float*)d_out);
}

// Round 5
// 562.347 us; speedup vs baseline: 1.3320x; 1.3320x over previous
//
#include <hip/hip_runtime.h>

typedef __attribute__((ext_vector_type(8))) short short8;
typedef __attribute__((ext_vector_type(4))) float f32x4;
typedef __attribute__((ext_vector_type(4))) int i32x4;

#define NPIX 65536
#define KPITCH 264
#define RED_KSUM 0
#define RED_VSUM 512
#define RED_AGG 1024

__device__ __forceinline__ float b2f(unsigned short u) {
  union { unsigned int i; float f; } z; z.i = ((unsigned int)u) << 16; return z.f;
}
__device__ __forceinline__ unsigned short f2b(float f) {
  union { float f; unsigned int i; } z; z.f = f;
  unsigned int r = z.i + 0x7fffu + ((z.i >> 16) & 1u);
  return (unsigned short)(r >> 16);
}
__device__ __forceinline__ unsigned int packbf(float a, float b) {
  return (unsigned int)f2b(a) | ((unsigned int)f2b(b) << 16);
}
// packed f32->bf16 (RNE), 1 instr per 2 values
__device__ __forceinline__ int cvtpk(float a, float b) {
  int r;
  asm("v_cvt_pk_bf16_f32 %0, %1, %2" : "=v"(r) : "v"(a), "v"(b));
  return r;
}

// Build MFMA A-fragment weights (bf16):
//  - wA[conv][tap][kb][mt][lane][j] = W[o=mt*16+(lane&15)][c=kb*32+(lane>>4)*8+j][tap]
//  - wQKV[pj][kb][mt][lane][j]      = Wp[o=mt*16+(lane&15)][c=kb*32+(lane>>4)*8+j]
//    (pj 0/1/2 = Wq/Wk/Wv; loop-invariant fragments hoisted out of qkv)
// Also zero the reduction region (ws is 0xAA-poisoned before every call).
__global__ __launch_bounds__(256) void prep_kernel(
    const float* __restrict__ W1, const float* __restrict__ W2,
    const float* __restrict__ Wq, const float* __restrict__ Wk,
    const float* __restrict__ Wv,
    unsigned short* __restrict__ wA, unsigned short* __restrict__ wQKV,
    float* __restrict__ red)
{
  const int i = blockIdx.x * 256 + threadIdx.x;
  if (i < 73728) {
    const float* W = (i < 36864) ? W1 : W2;
    const int e = (i < 36864) ? i : (i - 36864);
    const int j    = e & 7;
    const int lane = (e >> 3) & 63;
    const int mt   = (e >> 9) & 3;
    const int kb   = (e >> 11) & 1;
    const int tap  = e >> 12;                 // 0..8 = dy*3+dx
    const int o = mt * 16 + (lane & 15);
    const int c = kb * 32 + ((lane >> 4) << 3) + j;
    wA[i] = f2b(W[o * 576 + c * 9 + tap]);
  } else if (i < 86016) {
    const int e = i - 73728;                  // [pj][kb][mt][lane][j]
    const int j    = e & 7;
    const int lane = (e >> 3) & 63;
    const int mt   = (e >> 9) & 3;
    const int kb   = (e >> 11) & 1;
    const int pj   = e >> 12;                 // 0..2
    const float* W = (pj == 0) ? Wq : (pj == 1) ? Wk : Wv;
    const int o = mt * 16 + (lane & 15);
    const int c = kb * 32 + ((lane >> 4) << 3) + j;
    wQKV[e] = f2b(W[o * 64 + c]);
  } else if (i < 119808) {
    red[i - 86016] = 0.0f;
  }
}

// Pass 1 (R1 structure): Q/K/V via 16x16x32 bf16 MFMA, 256-px rounds,
// 64-px wave tiles. Q: L2-normalized, wave-private LDS transpose, dense
// NHWC bf16 store. K/V staged bf16 [64ch][KPITCH px] LDS; agg_kv = Kn.V^T
// via MFMA over k = pixels. Weight A-fragments pre-built in wQKV (prep) —
// PROJ is 8 L1-hot 16B loads + 32 MFMAs, no cvt chain on the critical path.
#define PROJ(PIDX, BM)                                                         \
    {                                                                          \
      _Pragma("unroll")                                                        \
      for (int mt = 0; mt < 4; ++mt) {                                         \
        const f32x4 bb = *(const f32x4*)((BM) + mt * 16 + g * 4);              \
        _Pragma("unroll")                                                      \
        for (int nt = 0; nt < 4; ++nt) acc[mt][nt] = bb;                       \
      }                                                                        \
      _Pragma("unroll")                                                        \
      for (int kb = 0; kb < 2; ++kb) {                                         \
        const unsigned short* wp = wQKV + ((PIDX) * 2 + kb) * 2048 + l * 8;    \
        short8 af[4];                                                          \
        _Pragma("unroll")                                                      \
        for (int mt = 0; mt < 4; ++mt)                                         \
          af[mt] = *(const short8*)(wp + mt * 512);                            \
        _Pragma("unroll")                                                      \
        for (int mt = 0; mt < 4; ++mt)                                         \
          _Pragma("unroll")                                                    \
          for (int nt = 0; nt < 4; ++nt)                                       \
            acc[mt][nt] = __builtin_amdgcn_mfma_f32_16x16x32_bf16(             \
                af[mt], bf[nt][kb], acc[mt][nt], 0, 0, 0);                     \
      }                                                                        \
    }

__global__ __launch_bounds__(256, 2) void qkv_kernel(
    const float* __restrict__ x,
    const unsigned short* __restrict__ wQKV,
    const float* __restrict__ bq, const float* __restrict__ bk,
    const float* __restrict__ bv,
    unsigned short* __restrict__ Qn, float* __restrict__ red)
{
  __shared__ __align__(16) unsigned short sh[2 * 64 * KPITCH];
  unsigned short* ks = sh;
  unsigned short* vs = sh + 64 * KPITCH;
  unsigned int* shu = (unsigned int*)sh;
  const int b = blockIdx.y;
  const int t = threadIdx.x;
  const int w = t >> 6;
  const int l = t & 63;
  const int g = l >> 4;
  const int l15 = l & 15;
  const size_t xb = (size_t)b * 64 * NPIX;

  const f32x4 zero = {0.f, 0.f, 0.f, 0.f};
  f32x4 agg[4]  = {zero, zero, zero, zero};
  f32x4 kacc[4] = {zero, zero, zero, zero};
  f32x4 vacc[4] = {zero, zero, zero, zero};

  for (int it = 0; it < 4; ++it) {
    const int pxw = (blockIdx.x << 10) + (it << 8) + (w << 6);  // wave px base

    // ---- x B-fragments (c-contiguous per lane), shared across Q,K,V ----
    short8 bf[4][2];
#pragma unroll
    for (int nt = 0; nt < 4; ++nt) {
      const float* xp = x + xb + (size_t)(g * 8) * NPIX + pxw + nt * 16 + l15;
#pragma unroll
      for (int kb = 0; kb < 2; ++kb) {
        float f[8];
#pragma unroll
        for (int j = 0; j < 8; ++j)
          f[j] = xp[(size_t)(kb * 32 + j) * NPIX];
        union { i32x4 i; short8 s; } u;
        u.i.x = cvtpk(f[0], f[1]); u.i.y = cvtpk(f[2], f[3]);
        u.i.z = cvtpk(f[4], f[5]); u.i.w = cvtpk(f[6], f[7]);
        bf[nt][kb] = u.s;
      }
    }

    f32x4 acc[4][4];

    // ---- Q: project, L2-normalize, LDS transpose, dense NHWC store ----
    PROJ(0, bq);
    {
      float rq[4];
#pragma unroll
      for (int nt = 0; nt < 4; ++nt) {
        float ss = 0.f;
#pragma unroll
        for (int mt = 0; mt < 4; ++mt)
#pragma unroll
          for (int r = 0; r < 4; ++r)
            ss = fmaf(acc[mt][nt][r], acc[mt][nt][r], ss);
        ss += __shfl_xor(ss, 16);
        ss += __shfl_xor(ss, 32);
        rq[nt] = rsqrtf(ss);
      }
      // wave-private transpose region (pitch 72 shorts = 36 uints per px)
      unsigned int* sw = shu + w * 2304;
#pragma unroll
      for (int mt = 0; mt < 4; ++mt)
#pragma unroll
        for (int nt = 0; nt < 4; ++nt) {
          const int px = nt * 16 + l15;
          unsigned int* dst = sw + px * 36 + mt * 8 + g * 2;
          dst[0] = (unsigned)cvtpk(acc[mt][nt][0] * rq[nt], acc[mt][nt][1] * rq[nt]);
          dst[1] = (unsigned)cvtpk(acc[mt][nt][2] * rq[nt], acc[mt][nt][3] * rq[nt]);
        }
      const uint4* rr4 = (const uint4*)(shu + w * 2304);   // 9 uint4 per px
#pragma unroll
      for (int k8 = 0; k8 < 8; ++k8) {
        const int p = (k8 << 3) + (l >> 3);
        const int ch8 = l & 7;
        *(uint4*)(Qn + ((size_t)b * NPIX + pxw + p) * 64 + ch8 * 8) =
            rr4[p * 9 + ch8];
      }
      __syncthreads();   // scratch overlaps ks/vs staging regions
    }

    // ---- K: project, normalize, accumulate ksum, stage to LDS ----
    PROJ(1, bk);
    {
      float rk[4];
#pragma unroll
      for (int nt = 0; nt < 4; ++nt) {
        float ss = 0.f;
#pragma unroll
        for (int mt = 0; mt < 4; ++mt)
#pragma unroll
          for (int r = 0; r < 4; ++r)
            ss = fmaf(acc[mt][nt][r], acc[mt][nt][r], ss);
        ss += __shfl_xor(ss, 16);
        ss += __shfl_xor(ss, 32);
        rk[nt] = rsqrtf(ss);
      }
#pragma unroll
      for (int mt = 0; mt < 4; ++mt)
#pragma unroll
        for (int nt = 0; nt < 4; ++nt)
#pragma unroll
          for (int r = 0; r < 4; ++r) {
            const float kn = acc[mt][nt][r] * rk[nt];
            kacc[mt][r] += kn;
            ks[(mt * 16 + g * 4 + r) * KPITCH + (w << 6) + nt * 16 + l15] =
                (unsigned short)cvtpk(kn, 0.f);
          }
    }

    // ---- V: project, accumulate vsum, stage to LDS ----
    PROJ(2, bv);
    {
#pragma unroll
      for (int mt = 0; mt < 4; ++mt)
#pragma unroll
        for (int nt = 0; nt < 4; ++nt)
#pragma unroll
          for (int r = 0; r < 4; ++r) {
            const float vv = acc[mt][nt][r];
            vacc[mt][r] += vv;
            vs[(mt * 16 + g * 4 + r) * KPITCH + (w << 6) + nt * 16 + l15] =
                (unsigned short)cvtpk(vv, 0.f);
          }
    }
    __syncthreads();

    // ---- agg_kv: MFMA over k = pixels (256 px this iter, 8 k-steps) ----
#pragma unroll
    for (int s = 0; s < 8; ++s) {
      const short8 ak =
          *(const short8*)(ks + (w * 16 + l15) * KPITCH + s * 32 + g * 8);
#pragma unroll
      for (int nt = 0; nt < 4; ++nt) {
        const short8 bv8 =
            *(const short8*)(vs + (nt * 16 + l15) * KPITCH + s * 32 + g * 8);
        agg[nt] = __builtin_amdgcn_mfma_f32_16x16x32_bf16(ak, bv8, agg[nt], 0, 0, 0);
      }
    }
    __syncthreads();
  }

  // ---- reductions: ksum/vsum butterfly over l&15, then global atomics ----
#pragma unroll
  for (int mt = 0; mt < 4; ++mt)
#pragma unroll
    for (int r = 0; r < 4; ++r) {
      float kv = kacc[mt][r], vv = vacc[mt][r];
#pragma unroll
      for (int d = 1; d < 16; d <<= 1) {
        kv += __shfl_xor(kv, d);
        vv += __shfl_xor(vv, d);
      }
      if (l15 == 0) {
        atomicAdd(red + RED_KSUM + b * 64 + mt * 16 + g * 4 + r, kv);
        atomicAdd(red + RED_VSUM + b * 64 + mt * 16 + g * 4 + r, vv);
      }
    }
  float* ab = red + RED_AGG + b * 4096;
#pragma unroll
  for (int nt = 0; nt < 4; ++nt)
#pragma unroll
    for (int r = 0; r < 4; ++r)
      atomicAdd(ab + (w * 16 + g * 4 + r) * 64 + nt * 16 + l15, agg[nt][r]);
}

// Prep2: per batch, C = Wr.agg^T (64x64) split into bf16 hi+residual in
// MFMA A-frag layout; u = Wr.vsum; ks2 = ksum + eps.
__global__ __launch_bounds__(256) void prep2_kernel(
    const float* __restrict__ Wr, const float* __restrict__ red,
    unsigned short* __restrict__ Cb, float* __restrict__ u,
    float* __restrict__ ks2)
{
  const int b = blockIdx.y;
  const int t = threadIdx.x;
  const int o = t & 63;
  const int kq = t >> 6;                 // 0..3
  const float* wr = Wr + o * 64;
  const float* agg = red + RED_AGG + b * 4096;
#pragma unroll
  for (int i = 0; i < 4; ++i) {
    const int k = blockIdx.x * 16 + kq * 4 + i;
    const float* ar = agg + k * 64;
    float s = 0.f;
#pragma unroll
    for (int v = 0; v < 64; ++v) s = fmaf(wr[v], ar[v], s);
    const int mt = o >> 4, kb = k >> 5;
    const int lane = (o & 15) | (((k >> 3) & 3) << 4);
    const int j = k & 7;
    const unsigned short c1 = f2b(s);
    const float r1 = s - b2f(c1);
    Cb[b * 4096 + ((kb * 4 + mt) * 64 + lane) * 8 + j] = c1;
    Cb[32768 + b * 4096 + ((kb * 4 + mt) * 64 + lane) * 8 + j] = f2b(r1);
  }
  if (blockIdx.x == 0 && t < 64) {
    const float* vsr = red + RED_VSUM + b * 64;
    float s = 0.f;
#pragma unroll
    for (int v = 0; v < 64; ++v) s = fmaf(Wr[t * 64 + v], vsr[v], s);
    u[b * 64 + t] = s;
    ks2[b * 64 + t] = red[RED_KSUM + b * 64 + t] + 1e-6f;
  }
}

// Pass 2 (MFMA): attn[o,n] = denom[n]*(u[o] + C[o,:].qn[:,n]) + br[o].
// C = C1 + C2 (bf16 split) -> fp32-accurate. denom from per-lane partial
// dot with ks2 + shfl_xor reduce. Output NHWC bf16 via wave-private LDS
// transpose (no barriers needed).
__global__ __launch_bounds__(256, 2) void attn_kernel(
    const unsigned short* __restrict__ Qn,   // NHWC bf16
    const unsigned short* __restrict__ Cb,   // C1||C2 A-frags
    const float* __restrict__ u,
    const float* __restrict__ ks2,
    const float* __restrict__ br,
    unsigned short* __restrict__ attn)       // NHWC bf16
{
  __shared__ __align__(16) unsigned short att[256 * 72];
  const int b = blockIdx.y;
  const int t = threadIdx.x;
  const int w = t >> 6, l = t & 63, g = l >> 4, l15 = l & 15;

  short8 af[2][2][4];  // [lvl][kb][mt]
#pragma unroll
  for (int lvl = 0; lvl < 2; ++lvl)
#pragma unroll
    for (int kb = 0; kb < 2; ++kb)
#pragma unroll
      for (int mt = 0; mt < 4; ++mt)
        af[lvl][kb][mt] = *(const short8*)(
            Cb + lvl * 32768 + b * 4096 + ((kb * 4 + mt) * 64 + l) * 8);
  f32x4 uu[4], brf[4];
#pragma unroll
  for (int mt = 0; mt < 4; ++mt) {
    uu[mt]  = *(const f32x4*)(u + b * 64 + mt * 16 + g * 4);
    brf[mt] = *(const f32x4*)(br + mt * 16 + g * 4);
  }
  float ksl[16];
#pragma unroll
  for (int kb = 0; kb < 2; ++kb)
#pragma unroll
    for (int j = 0; j < 8; ++j)
      ksl[kb * 8 + j] = ks2[b * 64 + kb * 32 + g * 8 + j];

  for (int it = 0; it < 4; ++it) {
    const int pxw = (blockIdx.x << 10) + (it << 8) + (w << 6);
    short8 qf[4][2];
    float denom[4];
#pragma unroll
    for (int nt = 0; nt < 4; ++nt) {
      const unsigned short* qp =
          Qn + ((size_t)b * NPIX + pxw + nt * 16 + l15) * 64 + g * 8;
      qf[nt][0] = *(const short8*)qp;
      qf[nt][1] = *(const short8*)(qp + 32);
      float ss = 0.f;
#pragma unroll
      for (int kb = 0; kb < 2; ++kb)
#pragma unroll
        for (int j = 0; j < 8; ++j)
          ss = fmaf(b2f((unsigned short)qf[nt][kb][j]), ksl[kb * 8 + j], ss);
      ss += __shfl_xor(ss, 16);
      ss += __shfl_xor(ss, 32);
      denom[nt] = 1.0f / (65536.0f + ss);
    }
    f32x4 acc[4][4];
#pragma unroll
    for (int mt = 0; mt < 4; ++mt)
#pragma unroll
      for (int nt = 0; nt < 4; ++nt) acc[mt][nt] = uu[mt];
#pragma unroll
    for (int kb = 0; kb < 2; ++kb)
#pragma unroll
      for (int mt = 0; mt < 4; ++mt)
#pragma unroll
        for (int nt = 0; nt < 4; ++nt) {
          acc[mt][nt] = __builtin_amdgcn_mfma_f32_16x16x32_bf16(
              af[0][kb][mt], qf[nt][kb], acc[mt][nt], 0, 0, 0);
          acc[mt][nt] = __builtin_amdgcn_mfma_f32_16x16x32_bf16(
              af[1][kb][mt], qf[nt][kb], acc[mt][nt], 0, 0, 0);
        }
    // epilogue: val = acc*denom + br; wave-private LDS transpose, dense store
    unsigned int* sw = (unsigned int*)att + w * 2304;
#pragma unroll
    for (int mt = 0; mt < 4; ++mt)
#pragma unroll
      for (int nt = 0; nt < 4; ++nt) {
        const int px = nt * 16 + l15;
        unsigned int* dst = sw + px * 36 + mt * 8 + g * 2;
        dst[0] = (unsigned)cvtpk(fmaf(acc[mt][nt][0], denom[nt], brf[mt][0]),
                                 fmaf(acc[mt][nt][1], denom[nt], brf[mt][1]));
        dst[1] = (unsigned)cvtpk(fmaf(acc[mt][nt][2], denom[nt], brf[mt][2]),
                                 fmaf(acc[mt][nt][3], denom[nt], brf[mt][3]));
      }
    const uint4* rr4 = (const uint4*)att + w * 576;
#pragma unroll
    for (int k8 = 0; k8 < 8; ++k8) {
      const int p = (k8 << 3) + (l >> 3);
      const int ch8 = l & 7;
      *(uint4*)(attn + ((size_t)b * NPIX + pxw + p) * 64 + ch8 * 8) =
          rr4[p * 9 + ch8];
    }
  }
}

// 3x3 SAME conv, 64->64 ch, bf16 MFMA implicit GEMM.
template <int EPI>
__global__ __launch_bounds__(256, 3) void conv3_kernel(
    const unsigned short* __restrict__ in,   // NHWC bf16
    const unsigned short* __restrict__ wA,   // A-frag weights bf16
    const float* __restrict__ bias,
    const float* __restrict__ xin,           // NCHW fp32 (EPI=1)
    unsigned short* __restrict__ outh,       // NHWC bf16 (EPI=0)
    float* __restrict__ outf)                // NCHW fp32 (EPI=1)
{
  __shared__ __align__(16) unsigned short tile[10 * 34 * 72];
  const int bz = blockIdx.z;
  const int ty0 = blockIdx.y << 3;
  const int tx0 = blockIdx.x << 5;
  const int tid = threadIdx.x;
  const size_t nb = (size_t)bz * NPIX;

  // ---- stage NHWC tile (halo=1, zero-pad SAME) ----
  for (int s = tid; s < 2720; s += 256) {
    const int g = s & 7;
    const int pix = s >> 3;          // 0..339
    const int xx = pix % 34;
    const int row = pix / 34;
    const int gx = tx0 + xx - 1;
    const int gy = ty0 + row - 1;
    uint4 v = {0u, 0u, 0u, 0u};
    if ((unsigned)gx < 256u && (unsigned)gy < 256u)
      v = *(const uint4*)(in + ((nb + (gy << 8) + gx) << 6) + (g << 3));
    *(uint4*)(tile + pix * 72 + (g << 3)) = v;
  }
  __syncthreads();

  const int w = tid >> 6, lane = tid & 63, q = lane >> 4, l = lane & 15;
  f32x4 acc[4][4];
  {
#pragma unroll
    for (int mt = 0; mt < 4; ++mt) {
      const f32x4 bb = *(const f32x4*)(bias + mt * 16 + q * 4);
#pragma unroll
      for (int nt = 0; nt < 4; ++nt) acc[mt][nt] = bb;
    }
  }
  const short8* tp = (const short8*)tile;   // 72 shorts = 9 short8 per pixel
  for (int tap = 0; tap < 9; ++tap) {
    const int dy = tap / 3, dx = tap - dy * 3;
#pragma unroll
    for (int kb = 0; kb < 2; ++kb) {
      const unsigned short* wp = wA + (tap * 2 + kb) * 2048 + lane * 8;
      short8 af[4];
#pragma unroll
      for (int mt = 0; mt < 4; ++mt) af[mt] = *(const short8*)(wp + mt * 512);
      short8 bf[4];
#pragma unroll
      for (int nt = 0; nt < 4; ++nt) {
        const int yl = (w << 1) + (nt >> 1) + dy;           // 0..9
        const int xl = ((nt & 1) << 4) + l + dx;            // 0..33
        bf[nt] = tp[(yl * 34 + xl) * 9 + (kb << 2) + q];
      }
#pragma unroll
      for (int mt = 0; mt < 4; ++mt)
#pragma unroll
        for (int nt = 0; nt < 4; ++nt)
          acc[mt][nt] = __builtin_amdgcn_mfma_f32_16x16x32_bf16(
              af[mt], bf[nt], acc[mt][nt], 0, 0, 0);
    }
  }

  if (EPI == 0) {
    // NHWC bf16 epilogue: transpose C-frag -> [pixel][o] in LDS, dense store
    __syncthreads();                          // all waves done reading tile
    unsigned int* wreg = (unsigned int*)tile + w * 2304;   // 64 px * 36 uints
#pragma unroll
    for (int mt = 0; mt < 4; ++mt)
#pragma unroll
      for (int nt = 0; nt < 4; ++nt) {
        const int p = ((nt >> 1) << 5) + ((nt & 1) << 4) + l;
        unsigned int* dst = wreg + p * 36 + (mt << 3) + (q << 1);
        dst[0] = packbf(acc[mt][nt][0], acc[mt][nt][1]);
        dst[1] = packbf(acc[mt][nt][2], acc[mt][nt][3]);
      }
    __syncthreads();
    const uint4* rreg = (const uint4*)tile + w * 576;      // 64 px * 9 uint4
#pragma unroll
    for (int k = 0; k < 8; ++k) {
      const int p = (k << 3) + (lane >> 3);
      const int ch = lane & 7;
      const int gx = tx0 + (p & 31);
      const int gy = ty0 + (w << 1) + (p >> 5);
      *(uint4*)(outh + ((nb + (gy << 8) + gx) << 6) + (ch << 3)) =
          rreg[p * 9 + ch];
    }
  } else {
    // fused epilogue: out = conv*x + x, NCHW fp32
#pragma unroll
    for (int mt = 0; mt < 4; ++mt)
#pragma unroll
      for (int nt = 0; nt < 4; ++nt) {
        const int gx = tx0 + ((nt & 1) << 4) + l;
        const int gy = ty0 + (w << 1) + (nt >> 1);
#pragma unroll
        for (int r = 0; r < 4; ++r) {
          const int o = (mt << 4) + (q << 2) + r;
          const size_t idx = (((size_t)bz * 64 + o) << 16) + (gy << 8) + gx;
          const float xo = xin[idx];
          outf[idx] = fmaf(acc[mt][nt][r], xo, xo);
        }
      }
  }
}

extern "C" void kernel_launch(void* const* d_in, const int* in_sizes, int n_in,
                              void* d_out, int out_size, void* d_ws, size_t ws_size,
                              hipStream_t stream) {
  (void)in_sizes; (void)n_in; (void)out_size; (void)ws_size;
  const float* x  = (const float*)d_in[0];
  const float* Wq = (const float*)d_in[1];
  const float* bq = (const float*)d_in[2];
  const float* Wk = (const float*)d_in[3];
  const float* bk = (const float*)d_in[4];
  const float* Wv = (const float*)d_in[5];
  const float* bv = (const float*)d_in[6];
  const float* Wr = (const float*)d_in[7];
  const float* br = (const float*)d_in[8];
  const float* W1 = (const float*)d_in[9];
  const float* b1 = (const float*)d_in[10];
  const float* W2 = (const float*)d_in[11];
  const float* b2 = (const float*)d_in[12];

  // ws layout: wA1 [0,73728B) | wA2 [73728,147456B) | red 33792 fp32 | bufA.
  // wQKV (24KB) aliases bufA's head: written by prep, read by qkv, then
  // overwritten by prep2's Cb (same region), read by attn, then overwritten
  // by conv3<0>'s bufA output (all stream-serialized).
  unsigned short* wA1 = (unsigned short*)d_ws;
  unsigned short* wA2 = wA1 + 36864;
  float* red = (float*)((char*)d_ws + 147456);
  unsigned short* bufA = (unsigned short*)((char*)d_ws + 294912); // conv1 out NHWC bf16
  unsigned short* wQKV = (unsigned short*)((char*)d_ws + 294912);
  unsigned short* Cb = (unsigned short*)((char*)d_ws + 294912);
  float* u_  = (float*)((char*)d_ws + 294912 + 131072);
  float* ks2 = (float*)((char*)d_ws + 294912 + 133120);
  // d_out scratch: first half = attn NHWC bf16, second half = Qn NHWC bf16.
  unsigned short* bufB = (unsigned short*)d_out;
  unsigned short* bufQ = (unsigned short*)((char*)d_out + 67108864);

  prep_kernel<<<468, 256, 0, stream>>>(W1, W2, Wq, Wk, Wv, wA1, wQKV, red);
  qkv_kernel<<<dim3(64, 8), 256, 0, stream>>>(x, wQKV, bq, bk, bv, bufQ, red);
  prep2_kernel<<<dim3(4, 8), 256, 0, stream>>>(Wr, red, Cb, u_, ks2);
  attn_kernel<<<dim3(64, 8), 256, 0, stream>>>(bufQ, Cb, u_, ks2, br, bufB);
  conv3_kernel<0><<<dim3(8, 32, 8), 256, 0, stream>>>(
      bufB, wA1, b1, nullptr, bufA, nullptr);
  conv3_kernel<1><<<dim3(8, 32, 8), 256, 0, stream>>>(
      bufA, wA2, b2, x, nullptr, (float*)d_out);
}

// Round 6
// 561.247 us; speedup vs baseline: 1.3346x; 1.0020x over previous
//
#include <hip/hip_runtime.h>

typedef __attribute__((ext_vector_type(8))) short short8;
typedef __attribute__((ext_vector_type(4))) float f32x4;
typedef __attribute__((ext_vector_type(4))) int i32x4;

#define NPIX 65536
#define KPITCH 264
#define RED_KSUM 0
#define RED_VSUM 512
#define RED_AGG 1024

__device__ __forceinline__ float b2f(unsigned short u) {
  union { unsigned int i; float f; } z; z.i = ((unsigned int)u) << 16; return z.f;
}
__device__ __forceinline__ unsigned short f2b(float f) {
  union { float f; unsigned int i; } z; z.f = f;
  unsigned int r = z.i + 0x7fffu + ((z.i >> 16) & 1u);
  return (unsigned short)(r >> 16);
}
__device__ __forceinline__ unsigned int packbf(float a, float b) {
  return (unsigned int)f2b(a) | ((unsigned int)f2b(b) << 16);
}
// packed f32->bf16 (RNE), 1 instr per 2 values
__device__ __forceinline__ int cvtpk(float a, float b) {
  int r;
  asm("v_cvt_pk_bf16_f32 %0, %1, %2" : "=v"(r) : "v"(a), "v"(b));
  return r;
}

// Build MFMA A-fragment weights (bf16):
//  - wA[conv][tap][kb][mt][lane][j] = W[o=mt*16+(lane&15)][c=kb*32+(lane>>4)*8+j][tap]
//  - wQKV[pj][kb][mt][lane][j]      = Wp[o=mt*16+(lane&15)][c=kb*32+(lane>>4)*8+j]
// Also zero the reduction region (ws is 0xAA-poisoned before every call).
__global__ __launch_bounds__(256) void prep_kernel(
    const float* __restrict__ W1, const float* __restrict__ W2,
    const float* __restrict__ Wq, const float* __restrict__ Wk,
    const float* __restrict__ Wv,
    unsigned short* __restrict__ wA, unsigned short* __restrict__ wQKV,
    float* __restrict__ red)
{
  const int i = blockIdx.x * 256 + threadIdx.x;
  if (i < 73728) {
    const float* W = (i < 36864) ? W1 : W2;
    const int e = (i < 36864) ? i : (i - 36864);
    const int j    = e & 7;
    const int lane = (e >> 3) & 63;
    const int mt   = (e >> 9) & 3;
    const int kb   = (e >> 11) & 1;
    const int tap  = e >> 12;                 // 0..8 = dy*3+dx
    const int o = mt * 16 + (lane & 15);
    const int c = kb * 32 + ((lane >> 4) << 3) + j;
    wA[i] = f2b(W[o * 576 + c * 9 + tap]);
  } else if (i < 86016) {
    const int e = i - 73728;                  // [pj][kb][mt][lane][j]
    const int j    = e & 7;
    const int lane = (e >> 3) & 63;
    const int mt   = (e >> 9) & 3;
    const int kb   = (e >> 11) & 1;
    const int pj   = e >> 12;                 // 0..2
    const float* W = (pj == 0) ? Wq : (pj == 1) ? Wk : Wv;
    const int o = mt * 16 + (lane & 15);
    const int c = kb * 32 + ((lane >> 4) << 3) + j;
    wQKV[e] = f2b(W[o * 64 + c]);
  } else if (i < 119808) {
    red[i - 86016] = 0.0f;
  }
}

// Pass 1: Q/K/V via 16x16x32 bf16 MFMA, 256-px rounds, 64-px wave tiles.
// Q: L2-normalized, wave-private LDS transpose, dense NHWC bf16 store.
// K/V staged bf16 [64ch][KPITCH px] LDS; agg_kv = Kn.V^T via MFMA over
// k = pixels. Weight A-fragments pre-built in wQKV (prep).
#define PROJ(PIDX, BM)                                                         \
    {                                                                          \
      _Pragma("unroll")                                                        \
      for (int mt = 0; mt < 4; ++mt) {                                         \
        const f32x4 bb = *(const f32x4*)((BM) + mt * 16 + g * 4);              \
        _Pragma("unroll")                                                      \
        for (int nt = 0; nt < 4; ++nt) acc[mt][nt] = bb;                       \
      }                                                                        \
      _Pragma("unroll")                                                        \
      for (int kb = 0; kb < 2; ++kb) {                                         \
        const unsigned short* wp = wQKV + ((PIDX) * 2 + kb) * 2048 + l * 8;    \
        short8 af[4];                                                          \
        _Pragma("unroll")                                                      \
        for (int mt = 0; mt < 4; ++mt)                                         \
          af[mt] = *(const short8*)(wp + mt * 512);                            \
        _Pragma("unroll")                                                      \
        for (int mt = 0; mt < 4; ++mt)                                         \
          _Pragma("unroll")                                                    \
          for (int nt = 0; nt < 4; ++nt)                                       \
            acc[mt][nt] = __builtin_amdgcn_mfma_f32_16x16x32_bf16(             \
                af[mt], bf[nt][kb], acc[mt][nt], 0, 0, 0);                     \
      }                                                                        \
    }

__global__ __launch_bounds__(256, 2) void qkv_kernel(
    const float* __restrict__ x,
    const unsigned short* __restrict__ wQKV,
    const float* __restrict__ bq, const float* __restrict__ bk,
    const float* __restrict__ bv,
    unsigned short* __restrict__ Qn, float* __restrict__ red)
{
  __shared__ __align__(16) unsigned short sh[2 * 64 * KPITCH];
  unsigned short* ks = sh;
  unsigned short* vs = sh + 64 * KPITCH;
  unsigned int* shu = (unsigned int*)sh;
  const int b = blockIdx.y;
  const int t = threadIdx.x;
  const int w = t >> 6;
  const int l = t & 63;
  const int g = l >> 4;
  const int l15 = l & 15;
  const size_t xb = (size_t)b * 64 * NPIX;

  const f32x4 zero = {0.f, 0.f, 0.f, 0.f};
  f32x4 agg[4]  = {zero, zero, zero, zero};
  f32x4 kacc[4] = {zero, zero, zero, zero};
  f32x4 vacc[4] = {zero, zero, zero, zero};

  for (int it = 0; it < 4; ++it) {
    const int pxw = (blockIdx.x << 10) + (it << 8) + (w << 6);  // wave px base

    // ---- x B-fragments (c-contiguous per lane), shared across Q,K,V ----
    short8 bf[4][2];
#pragma unroll
    for (int nt = 0; nt < 4; ++nt) {
      const float* xp = x + xb + (size_t)(g * 8) * NPIX + pxw + nt * 16 + l15;
#pragma unroll
      for (int kb = 0; kb < 2; ++kb) {
        float f[8];
#pragma unroll
        for (int j = 0; j < 8; ++j)
          f[j] = xp[(size_t)(kb * 32 + j) * NPIX];
        union { i32x4 i; short8 s; } u;
        u.i.x = cvtpk(f[0], f[1]); u.i.y = cvtpk(f[2], f[3]);
        u.i.z = cvtpk(f[4], f[5]); u.i.w = cvtpk(f[6], f[7]);
        bf[nt][kb] = u.s;
      }
    }

    f32x4 acc[4][4];

    // ---- Q: project, L2-normalize, LDS transpose, dense NHWC store ----
    PROJ(0, bq);
    {
      float rq[4];
#pragma unroll
      for (int nt = 0; nt < 4; ++nt) {
        float ss = 0.f;
#pragma unroll
        for (int mt = 0; mt < 4; ++mt)
#pragma unroll
          for (int r = 0; r < 4; ++r)
            ss = fmaf(acc[mt][nt][r], acc[mt][nt][r], ss);
        ss += __shfl_xor(ss, 16);
        ss += __shfl_xor(ss, 32);
        rq[nt] = rsqrtf(ss);
      }
      // wave-private transpose region (pitch 72 shorts = 36 uints per px)
      unsigned int* sw = shu + w * 2304;
#pragma unroll
      for (int mt = 0; mt < 4; ++mt)
#pragma unroll
        for (int nt = 0; nt < 4; ++nt) {
          const int px = nt * 16 + l15;
          unsigned int* dst = sw + px * 36 + mt * 8 + g * 2;
          dst[0] = (unsigned)cvtpk(acc[mt][nt][0] * rq[nt], acc[mt][nt][1] * rq[nt]);
          dst[1] = (unsigned)cvtpk(acc[mt][nt][2] * rq[nt], acc[mt][nt][3] * rq[nt]);
        }
      const uint4* rr4 = (const uint4*)(shu + w * 2304);   // 9 uint4 per px
#pragma unroll
      for (int k8 = 0; k8 < 8; ++k8) {
        const int p = (k8 << 3) + (l >> 3);
        const int ch8 = l & 7;
        *(uint4*)(Qn + ((size_t)b * NPIX + pxw + p) * 64 + ch8 * 8) =
            rr4[p * 9 + ch8];
      }
      __syncthreads();   // scratch overlaps ks/vs staging regions
    }

    // ---- K: project, normalize, accumulate ksum, stage to LDS ----
    PROJ(1, bk);
    {
      float rk[4];
#pragma unroll
      for (int nt = 0; nt < 4; ++nt) {
        float ss = 0.f;
#pragma unroll
        for (int mt = 0; mt < 4; ++mt)
#pragma unroll
          for (int r = 0; r < 4; ++r)
            ss = fmaf(acc[mt][nt][r], acc[mt][nt][r], ss);
        ss += __shfl_xor(ss, 16);
        ss += __shfl_xor(ss, 32);
        rk[nt] = rsqrtf(ss);
      }
#pragma unroll
      for (int mt = 0; mt < 4; ++mt)
#pragma unroll
        for (int nt = 0; nt < 4; ++nt)
#pragma unroll
          for (int r = 0; r < 4; ++r) {
            const float kn = acc[mt][nt][r] * rk[nt];
            kacc[mt][r] += kn;
            ks[(mt * 16 + g * 4 + r) * KPITCH + (w << 6) + nt * 16 + l15] =
                (unsigned short)cvtpk(kn, 0.f);
          }
    }

    // ---- V: project, accumulate vsum, stage to LDS ----
    PROJ(2, bv);
    {
#pragma unroll
      for (int mt = 0; mt < 4; ++mt)
#pragma unroll
        for (int nt = 0; nt < 4; ++nt)
#pragma unroll
          for (int r = 0; r < 4; ++r) {
            const float vv = acc[mt][nt][r];
            vacc[mt][r] += vv;
            vs[(mt * 16 + g * 4 + r) * KPITCH + (w << 6) + nt * 16 + l15] =
                (unsigned short)cvtpk(vv, 0.f);
          }
    }
    __syncthreads();

    // ---- agg_kv: MFMA over k = pixels (256 px this iter, 8 k-steps) ----
#pragma unroll
    for (int s = 0; s < 8; ++s) {
      const short8 ak =
          *(const short8*)(ks + (w * 16 + l15) * KPITCH + s * 32 + g * 8);
#pragma unroll
      for (int nt = 0; nt < 4; ++nt) {
        const short8 bv8 =
            *(const short8*)(vs + (nt * 16 + l15) * KPITCH + s * 32 + g * 8);
        agg[nt] = __builtin_amdgcn_mfma_f32_16x16x32_bf16(ak, bv8, agg[nt], 0, 0, 0);
      }
    }
    __syncthreads();
  }

  // ---- reductions: ksum/vsum butterfly over l&15, then global atomics ----
#pragma unroll
  for (int mt = 0; mt < 4; ++mt)
#pragma unroll
    for (int r = 0; r < 4; ++r) {
      float kv = kacc[mt][r], vv = vacc[mt][r];
#pragma unroll
      for (int d = 1; d < 16; d <<= 1) {
        kv += __shfl_xor(kv, d);
        vv += __shfl_xor(vv, d);
      }
      if (l15 == 0) {
        atomicAdd(red + RED_KSUM + b * 64 + mt * 16 + g * 4 + r, kv);
        atomicAdd(red + RED_VSUM + b * 64 + mt * 16 + g * 4 + r, vv);
      }
    }
  float* ab = red + RED_AGG + b * 4096;
#pragma unroll
  for (int nt = 0; nt < 4; ++nt)
#pragma unroll
    for (int r = 0; r < 4; ++r)
      atomicAdd(ab + (w * 16 + g * 4 + r) * 64 + nt * 16 + l15, agg[nt][r]);
}

// Prep2: per batch, C = Wr.agg^T (64x64) split into bf16 hi+residual in
// MFMA A-frag layout; u = Wr.vsum; ks2 = ksum + eps.
__global__ __launch_bounds__(256) void prep2_kernel(
    const float* __restrict__ Wr, const float* __restrict__ red,
    unsigned short* __restrict__ Cb, float* __restrict__ u,
    float* __restrict__ ks2)
{
  const int b = blockIdx.y;
  const int t = threadIdx.x;
  const int o = t & 63;
  const int kq = t >> 6;                 // 0..3
  const float* wr = Wr + o * 64;
  const float* agg = red + RED_AGG + b * 4096;
#pragma unroll
  for (int i = 0; i < 4; ++i) {
    const int k = blockIdx.x * 16 + kq * 4 + i;
    const float* ar = agg + k * 64;
    float s = 0.f;
#pragma unroll
    for (int v = 0; v < 64; ++v) s = fmaf(wr[v], ar[v], s);
    const int mt = o >> 4, kb = k >> 5;
    const int lane = (o & 15) | (((k >> 3) & 3) << 4);
    const int j = k & 7;
    const unsigned short c1 = f2b(s);
    const float r1 = s - b2f(c1);
    Cb[b * 4096 + ((kb * 4 + mt) * 64 + lane) * 8 + j] = c1;
    Cb[32768 + b * 4096 + ((kb * 4 + mt) * 64 + lane) * 8 + j] = f2b(r1);
  }
  if (blockIdx.x == 0 && t < 64) {
    const float* vsr = red + RED_VSUM + b * 64;
    float s = 0.f;
#pragma unroll
    for (int v = 0; v < 64; ++v) s = fmaf(Wr[t * 64 + v], vsr[v], s);
    u[b * 64 + t] = s;
    ks2[b * 64 + t] = red[RED_KSUM + b * 64 + t] + 1e-6f;
  }
}

// Pass 2 (MFMA): attn[o,n] = denom[n]*(u[o] + C[o,:].qn[:,n]) + br[o].
// Output NHWC bf16 (to ws bufB) via wave-private LDS transpose.
__global__ __launch_bounds__(256, 2) void attn_kernel(
    const unsigned short* __restrict__ Qn,   // NHWC bf16
    const unsigned short* __restrict__ Cb,   // C1||C2 A-frags
    const float* __restrict__ u,
    const float* __restrict__ ks2,
    const float* __restrict__ br,
    unsigned short* __restrict__ attn)       // NHWC bf16
{
  __shared__ __align__(16) unsigned short att[256 * 72];
  const int b = blockIdx.y;
  const int t = threadIdx.x;
  const int w = t >> 6, l = t & 63, g = l >> 4, l15 = l & 15;

  short8 af[2][2][4];  // [lvl][kb][mt]
#pragma unroll
  for (int lvl = 0; lvl < 2; ++lvl)
#pragma unroll
    for (int kb = 0; kb < 2; ++kb)
#pragma unroll
      for (int mt = 0; mt < 4; ++mt)
        af[lvl][kb][mt] = *(const short8*)(
            Cb + lvl * 32768 + b * 4096 + ((kb * 4 + mt) * 64 + l) * 8);
  f32x4 uu[4], brf[4];
#pragma unroll
  for (int mt = 0; mt < 4; ++mt) {
    uu[mt]  = *(const f32x4*)(u + b * 64 + mt * 16 + g * 4);
    brf[mt] = *(const f32x4*)(br + mt * 16 + g * 4);
  }
  float ksl[16];
#pragma unroll
  for (int kb = 0; kb < 2; ++kb)
#pragma unroll
    for (int j = 0; j < 8; ++j)
      ksl[kb * 8 + j] = ks2[b * 64 + kb * 32 + g * 8 + j];

  for (int it = 0; it < 4; ++it) {
    const int pxw = (blockIdx.x << 10) + (it << 8) + (w << 6);
    short8 qf[4][2];
    float denom[4];
#pragma unroll
    for (int nt = 0; nt < 4; ++nt) {
      const unsigned short* qp =
          Qn + ((size_t)b * NPIX + pxw + nt * 16 + l15) * 64 + g * 8;
      qf[nt][0] = *(const short8*)qp;
      qf[nt][1] = *(const short8*)(qp + 32);
      float ss = 0.f;
#pragma unroll
      for (int kb = 0; kb < 2; ++kb)
#pragma unroll
        for (int j = 0; j < 8; ++j)
          ss = fmaf(b2f((unsigned short)qf[nt][kb][j]), ksl[kb * 8 + j], ss);
      ss += __shfl_xor(ss, 16);
      ss += __shfl_xor(ss, 32);
      denom[nt] = 1.0f / (65536.0f + ss);
    }
    f32x4 acc[4][4];
#pragma unroll
    for (int mt = 0; mt < 4; ++mt)
#pragma unroll
      for (int nt = 0; nt < 4; ++nt) acc[mt][nt] = uu[mt];
#pragma unroll
    for (int kb = 0; kb < 2; ++kb)
#pragma unroll
      for (int mt = 0; mt < 4; ++mt)
#pragma unroll
        for (int nt = 0; nt < 4; ++nt) {
          acc[mt][nt] = __builtin_amdgcn_mfma_f32_16x16x32_bf16(
              af[0][kb][mt], qf[nt][kb], acc[mt][nt], 0, 0, 0);
          acc[mt][nt] = __builtin_amdgcn_mfma_f32_16x16x32_bf16(
              af[1][kb][mt], qf[nt][kb], acc[mt][nt], 0, 0, 0);
        }
    // epilogue: val = acc*denom + br; wave-private LDS transpose, dense store
    unsigned int* sw = (unsigned int*)att + w * 2304;
#pragma unroll
    for (int mt = 0; mt < 4; ++mt)
#pragma unroll
      for (int nt = 0; nt < 4; ++nt) {
        const int px = nt * 16 + l15;
        unsigned int* dst = sw + px * 36 + mt * 8 + g * 2;
        dst[0] = (unsigned)cvtpk(fmaf(acc[mt][nt][0], denom[nt], brf[mt][0]),
                                 fmaf(acc[mt][nt][1], denom[nt], brf[mt][1]));
        dst[1] = (unsigned)cvtpk(fmaf(acc[mt][nt][2], denom[nt], brf[mt][2]),
                                 fmaf(acc[mt][nt][3], denom[nt], brf[mt][3]));
      }
    const uint4* rr4 = (const uint4*)att + w * 576;
#pragma unroll
    for (int k8 = 0; k8 < 8; ++k8) {
      const int p = (k8 << 3) + (l >> 3);
      const int ch8 = l & 7;
      *(uint4*)(attn + ((size_t)b * NPIX + pxw + p) * 64 + ch8 * 8) =
          rr4[p * 9 + ch8];
    }
  }
}

// Fused double 3x3 SAME conv (64->64->64) + residual, bf16 MFMA.
// Per block: 8x32 out. conv1 computes the 10x34 halo'd intermediate
// directly from global attn (NHWC, per-lane predicated loads, L1/L2-hot
// tap re-reads), writes bf16 NHWC into LDS mid (image-border -> 0 for
// conv2 SAME). Barrier. conv2 (wave w = out row w, 32 cols, acc[4][2])
// + fused *x+x fp32 NCHW epilogue. 49KB LDS -> 2 blocks/CU of 512 thr.
__global__ __launch_bounds__(512, 2) void fused_conv_kernel(
    const unsigned short* __restrict__ in,   // attn NHWC bf16 (ws)
    const unsigned short* __restrict__ wA,   // wA1 | wA2 at +36864 shorts
    const float* __restrict__ b1, const float* __restrict__ b2,
    const float* __restrict__ xin,           // NCHW fp32
    float* __restrict__ outf)                // NCHW fp32
{
  __shared__ __align__(16) unsigned short mid[340 * 72];
  const int bz = blockIdx.z;
  const int ty0 = blockIdx.y << 3;
  const int tx0 = blockIdx.x << 5;
  const int tid = threadIdx.x;
  const int w = tid >> 6, lane = tid & 63, q = lane >> 4, l = lane & 15;
  const size_t nb = (size_t)bz * NPIX;

  if (w < 6) {
    // ---- conv1: wave w owns mid px mp = w*64 + nt*16 + l (mask mp<340) ----
    f32x4 acc[4][4];
#pragma unroll
    for (int mt = 0; mt < 4; ++mt) {
      const f32x4 bb = *(const f32x4*)(b1 + mt * 16 + q * 4);
#pragma unroll
      for (int nt = 0; nt < 4; ++nt) acc[mt][nt] = bb;
    }
    int ylv[4], xlv[4];
#pragma unroll
    for (int nt = 0; nt < 4; ++nt) {
      const int mp = w * 64 + nt * 16 + l;
      const int mpc = mp < 340 ? mp : 339;
      ylv[nt] = mpc / 34;                 // mid row 0..9
      xlv[nt] = mpc - ylv[nt] * 34;       // mid col 0..33
    }
    for (int tap = 0; tap < 9; ++tap) {
      const int dy = tap / 3, dx = tap - dy * 3;
#pragma unroll
      for (int kb = 0; kb < 2; ++kb) {
        const unsigned short* wp = wA + (tap * 2 + kb) * 2048 + lane * 8;
        short8 af[4];
#pragma unroll
        for (int mt = 0; mt < 4; ++mt) af[mt] = *(const short8*)(wp + mt * 512);
        short8 bfv[4];
#pragma unroll
        for (int nt = 0; nt < 4; ++nt) {
          const int gy = ty0 + ylv[nt] + dy - 2;    // input row (SAME pad)
          const int gx = tx0 + xlv[nt] + dx - 2;
          short8 v = {0, 0, 0, 0, 0, 0, 0, 0};
          if ((unsigned)gy < 256u && (unsigned)gx < 256u)
            v = *(const short8*)(
                in + ((nb + (gy << 8) + gx) << 6) + ((kb * 4 + q) << 3));
          bfv[nt] = v;
        }
#pragma unroll
        for (int mt = 0; mt < 4; ++mt)
#pragma unroll
          for (int nt = 0; nt < 4; ++nt)
            acc[mt][nt] = __builtin_amdgcn_mfma_f32_16x16x32_bf16(
                af[mt], bfv[nt], acc[mt][nt], 0, 0, 0);
      }
    }
    // ---- mid NHWC bf16 write; zero outside image (conv2 SAME pad) ----
    unsigned int* mu = (unsigned int*)mid;
#pragma unroll
    for (int nt = 0; nt < 4; ++nt) {
      const int mp = w * 64 + nt * 16 + l;
      if (mp < 340) {
        const int gym = ty0 + ylv[nt] - 1;
        const int gxm = tx0 + xlv[nt] - 1;
        const bool ok = ((unsigned)gym < 256u) && ((unsigned)gxm < 256u);
#pragma unroll
        for (int mt = 0; mt < 4; ++mt) {
          unsigned int* dst = mu + mp * 36 + mt * 8 + q * 2;
          dst[0] = ok ? packbf(acc[mt][nt][0], acc[mt][nt][1]) : 0u;
          dst[1] = ok ? packbf(acc[mt][nt][2], acc[mt][nt][3]) : 0u;
        }
      }
    }
  }
  __syncthreads();

  // ---- conv2: wave w -> out row ty0+w, 32 cols; then fused *x+x ----
  f32x4 acc2[4][2];
#pragma unroll
  for (int mt = 0; mt < 4; ++mt) {
    const f32x4 bb = *(const f32x4*)(b2 + mt * 16 + q * 4);
    acc2[mt][0] = bb; acc2[mt][1] = bb;
  }
  const short8* tp2 = (const short8*)mid;   // 9 short8 per mid pixel
  const unsigned short* wA2p = wA + 36864;
  for (int tap = 0; tap < 9; ++tap) {
    const int dy = tap / 3, dx = tap - dy * 3;
#pragma unroll
    for (int kb = 0; kb < 2; ++kb) {
      const unsigned short* wp = wA2p + (tap * 2 + kb) * 2048 + lane * 8;
      short8 af[4];
#pragma unroll
      for (int mt = 0; mt < 4; ++mt) af[mt] = *(const short8*)(wp + mt * 512);
      short8 bf2[2];
#pragma unroll
      for (int nt = 0; nt < 2; ++nt) {
        const int yl = w + dy;                    // 0..9
        const int xl = nt * 16 + l + dx;          // 0..33
        bf2[nt] = tp2[(yl * 34 + xl) * 9 + (kb << 2) + q];
      }
#pragma unroll
      for (int mt = 0; mt < 4; ++mt)
#pragma unroll
        for (int nt = 0; nt < 2; ++nt)
          acc2[mt][nt] = __builtin_amdgcn_mfma_f32_16x16x32_bf16(
              af[mt], bf2[nt], acc2[mt][nt], 0, 0, 0);
    }
  }
#pragma unroll
  for (int mt = 0; mt < 4; ++mt)
#pragma unroll
    for (int nt = 0; nt < 2; ++nt) {
      const int gx = tx0 + nt * 16 + l;
      const int gy = ty0 + w;
#pragma unroll
      for (int r = 0; r < 4; ++r) {
        const int o = (mt << 4) + (q << 2) + r;
        const size_t idx = (((size_t)bz * 64 + o) << 16) + (gy << 8) + gx;
        const float xo = xin[idx];
        outf[idx] = fmaf(acc2[mt][nt][r], xo, xo);
      }
    }
}

extern "C" void kernel_launch(void* const* d_in, const int* in_sizes, int n_in,
                              void* d_out, int out_size, void* d_ws, size_t ws_size,
                              hipStream_t stream) {
  (void)in_sizes; (void)n_in; (void)out_size; (void)ws_size;
  const float* x  = (const float*)d_in[0];
  const float* Wq = (const float*)d_in[1];
  const float* bq = (const float*)d_in[2];
  const float* Wk = (const float*)d_in[3];
  const float* bk = (const float*)d_in[4];
  const float* Wv = (const float*)d_in[5];
  const float* bv = (const float*)d_in[6];
  const float* Wr = (const float*)d_in[7];
  const float* br = (const float*)d_in[8];
  const float* W1 = (const float*)d_in[9];
  const float* b1 = (const float*)d_in[10];
  const float* W2 = (const float*)d_in[11];
  const float* b2 = (const float*)d_in[12];

  // ws layout (tightly overlapped by lifetime; peak < previous 67.4MB use):
  //  wA1 [0,73728) wA2 [73728,147456)          -- live until fused conv
  //  wQKV [147456,172032)                      -- prep->qkv, then dead
  //  Cb  [147456,278528) (overwrites wQKV)     -- prep2->attn
  //  u   [278528,280576)  ks2 [280576,282624)  -- prep2->attn
  //  red [282624,417824)                       -- prep/qkv->prep2, then dead
  //  bufB[282624,67391488) (overwrites red)    -- attn->fused conv
  unsigned short* wA1  = (unsigned short*)d_ws;
  unsigned short* wQKV = (unsigned short*)((char*)d_ws + 147456);
  unsigned short* Cb   = (unsigned short*)((char*)d_ws + 147456);
  float* u_  = (float*)((char*)d_ws + 278528);
  float* ks2 = (float*)((char*)d_ws + 280576);
  float* red = (float*)((char*)d_ws + 282624);
  unsigned short* bufB = (unsigned short*)((char*)d_ws + 282624);
  // d_out scratch: second half = Qn NHWC bf16 (consumed by attn before
  // fused conv overwrites all of d_out with the final fp32 NCHW output).
  unsigned short* bufQ = (unsigned short*)((char*)d_out + 67108864);

  prep_kernel<<<468, 256, 0, stream>>>(W1, W2, Wq, Wk, Wv, wA1, wQKV, red);
  qkv_kernel<<<dim3(64, 8), 256, 0, stream>>>(x, wQKV, bq, bk, bv, bufQ, red);
  prep2_kernel<<<dim3(4, 8), 256, 0, stream>>>(Wr, red, Cb, u_, ks2);
  attn_kernel<<<dim3(64, 8), 256, 0, stream>>>(bufQ, Cb, u_, ks2, br, bufB);
  fused_conv_kernel<<<dim3(8, 32, 8), 512, 0, stream>>>(
      bufB, wA1, b1, b2, x, (float*)d_out);
}